// Round 5
// baseline (22.717 us; speedup 1.0000x reference)
//
#include <hip/hip_runtime.h>
#include <hip/hip_bf16.h>

#define NQ 6
#define DIM 64
#define NLAYERS 6

typedef __attribute__((ext_vector_type(8))) short bf16x8;
typedef __attribute__((ext_vector_type(4))) float f32x4;

// ---------------------------------------------------------------------------
// build_M: fused circuit matrix M = P*U5*...*P*U0*F (complex 64x64), emitted
// directly as MFMA B-fragments in bf16 hi/lo split, frag-linear:
//   frag index f = (jt*2 + chunk)*4 + plane   (plane: 0=r_hi 1=r_lo 2=i_hi 3=i_lo)
//   ushort addr  = f*512 + lane16*8 + e
// where for element M[j][k]: jt=j>>4, lane16=(j&15)+16*((k>>3)&3), chunk=k>>5,
// e=k&7.  A-frags in qenc_main use the SAME (lane,elem)->k mapping, so the
// MFMA positional pairing is consistent regardless of the HW's internal order.
// ---------------------------------------------------------------------------
__global__ __launch_bounds__(64) void build_M(const float* __restrict__ w,
                                              unsigned short* __restrict__ Bf) {
    const int k = blockIdx.x;    // column 0..63
    const int j = threadIdx.x;   // row/lane 0..63

    int t = (j * k) & 63;
    float sv, cv;
    sincospif((float)t / 32.0f, &sv, &cv);   // exp(i*pi*t/32)
    float vr = cv * 0.125f;
    float vi = sv * 0.125f;

    // CNOT-ring composite destination lane (push), same every layer
    int m = j;
#pragma unroll
    for (int q = 0; q < NQ; ++q) {
        int cb = 5 - q;
        int tb = 5 - ((q + 1) % NQ);
        if ((m >> cb) & 1) m ^= (1 << tb);
    }
    const int dst4 = m << 2;

    for (int l = 0; l < NLAYERS; ++l) {
#pragma unroll
        for (int q = 0; q < NQ; ++q) {
            float th = w[l * NQ + q] * 0.5f;
            float c = cosf(th), s = sinf(th);
            int b = 5 - q;
            float pr = __shfl_xor(vr, 1 << b);
            float pi = __shfl_xor(vi, 1 << b);
            float sgn = ((j >> b) & 1) ? s : -s;
            vr = c * vr + sgn * pr;
            vi = c * vi + sgn * pi;
        }
        vr = __int_as_float(__builtin_amdgcn_ds_permute(dst4, __float_as_int(vr)));
        vi = __int_as_float(__builtin_amdgcn_ds_permute(dst4, __float_as_int(vi)));
    }

    // bf16 hi/lo split and scatter into fragment layout (ushort units)
    const int jt = j >> 4;
    const int lane16 = (j & 15) + 16 * ((k >> 3) & 3);
    const int chunk = k >> 5;
    const int e = k & 7;
    const int base = ((jt * 2 + chunk) * 4) * 512 + lane16 * 8 + e;

    __hip_bfloat16 rh = __float2bfloat16(vr);
    __hip_bfloat16 rl = __float2bfloat16(vr - __bfloat162float(rh));
    __hip_bfloat16 ih = __float2bfloat16(vi);
    __hip_bfloat16 il = __float2bfloat16(vi - __bfloat162float(ih));
    Bf[base]        = *(unsigned short*)&rh;
    Bf[base + 512]  = *(unsigned short*)&rl;
    Bf[base + 1024] = *(unsigned short*)&ih;
    Bf[base + 1536] = *(unsigned short*)&il;
}

// ---------------------------------------------------------------------------
// split 8 floats into bf16 hi + lo fragments
// ---------------------------------------------------------------------------
__device__ __forceinline__ void split8(const float* f, bf16x8& h, bf16x8& l) {
#pragma unroll
    for (int i = 0; i < 8; ++i) {
        __hip_bfloat16 hh = __float2bfloat16(f[i]);
        __hip_bfloat16 ll = __float2bfloat16(f[i] - __bfloat162float(hh));
        h[i] = *(short*)&hh;
        l[i] = *(short*)&ll;
    }
}

// ---------------------------------------------------------------------------
// qenc_main: no LDS, no barrier. Each wave owns 32 rows (two 16-row A-tiles).
// B-fragments stream straight from global (L2/L3-resident) into VGPRs inside
// the fully-unrolled jt loop: 12 MFMA per 4 B-loads, 8 independent acc chains.
// ---------------------------------------------------------------------------
__global__ __launch_bounds__(256) void qenc_main(const float* __restrict__ x,
                                                 const unsigned short* __restrict__ Bf,
                                                 float* __restrict__ out) {
    const int tid = threadIdx.x;
    const int lane = tid & 63;
    const int wid = tid >> 6;
    const int row0 = blockIdx.x * 128 + wid * 32;
    const int r = lane & 15;      // A row within tile
    const int g = lane >> 4;      // k-group

    // ---- x loads: two tiles, 16 floats each per lane
    const float* xp0 = x + (size_t)(row0 + r) * DIM + 8 * g;
    const float* xp1 = xp0 + (size_t)16 * DIM;
    float xf0[16], xf1[16];
    *(float4*)(xf0)      = *(const float4*)(xp0);
    *(float4*)(xf0 + 4)  = *(const float4*)(xp0 + 4);
    *(float4*)(xf0 + 8)  = *(const float4*)(xp0 + 32);
    *(float4*)(xf0 + 12) = *(const float4*)(xp0 + 36);
    *(float4*)(xf1)      = *(const float4*)(xp1);
    *(float4*)(xf1 + 4)  = *(const float4*)(xp1 + 4);
    *(float4*)(xf1 + 8)  = *(const float4*)(xp1 + 32);
    *(float4*)(xf1 + 12) = *(const float4*)(xp1 + 36);

    // ---- norms (reduce over the 4 lanes sharing row r)
    float n0 = 0.f, n1 = 0.f;
#pragma unroll
    for (int i = 0; i < 16; ++i) {
        n0 = fmaf(xf0[i], xf0[i], n0);
        n1 = fmaf(xf1[i], xf1[i], n1);
    }
    n0 += __shfl_xor(n0, 16);  n0 += __shfl_xor(n0, 32);
    n1 += __shfl_xor(n1, 16);  n1 += __shfl_xor(n1, 32);
    const float inv0 = 1.0f / n0;
    const float inv1 = 1.0f / n1;

    // ---- hi/lo bf16 A-fragments (chunk c: k = 32c + 8g .. +7)
    bf16x8 a0h[2], a0l[2], a1h[2], a1l[2];
    split8(xf0,     a0h[0], a0l[0]);
    split8(xf0 + 8, a0h[1], a0l[1]);
    split8(xf1,     a1h[0], a1l[0]);
    split8(xf1 + 8, a1h[1], a1l[1]);

    // ---- MFMA main: stream B-frags from global (each lane its own 16B)
    const f32x4 z = {0.f, 0.f, 0.f, 0.f};
    f32x4 acr0[4] = {z, z, z, z}, aci0[4] = {z, z, z, z};
    f32x4 acr1[4] = {z, z, z, z}, aci1[4] = {z, z, z, z};
    const bf16x8* bb = (const bf16x8*)Bf + lane;   // frag f at bb[f*64]

#pragma unroll
    for (int jt = 0; jt < 4; ++jt) {
#pragma unroll
        for (int c = 0; c < 2; ++c) {
            const int f0 = (jt * 2 + c) * 4;
            bf16x8 brh = bb[(f0 + 0) * 64];
            bf16x8 brl = bb[(f0 + 1) * 64];
            bf16x8 bih = bb[(f0 + 2) * 64];
            bf16x8 bil = bb[(f0 + 3) * 64];
            acr0[jt] = __builtin_amdgcn_mfma_f32_16x16x32_bf16(a0h[c], brh, acr0[jt], 0, 0, 0);
            acr0[jt] = __builtin_amdgcn_mfma_f32_16x16x32_bf16(a0h[c], brl, acr0[jt], 0, 0, 0);
            acr0[jt] = __builtin_amdgcn_mfma_f32_16x16x32_bf16(a0l[c], brh, acr0[jt], 0, 0, 0);
            aci0[jt] = __builtin_amdgcn_mfma_f32_16x16x32_bf16(a0h[c], bih, aci0[jt], 0, 0, 0);
            aci0[jt] = __builtin_amdgcn_mfma_f32_16x16x32_bf16(a0h[c], bil, aci0[jt], 0, 0, 0);
            aci0[jt] = __builtin_amdgcn_mfma_f32_16x16x32_bf16(a0l[c], bih, aci0[jt], 0, 0, 0);
            acr1[jt] = __builtin_amdgcn_mfma_f32_16x16x32_bf16(a1h[c], brh, acr1[jt], 0, 0, 0);
            acr1[jt] = __builtin_amdgcn_mfma_f32_16x16x32_bf16(a1h[c], brl, acr1[jt], 0, 0, 0);
            acr1[jt] = __builtin_amdgcn_mfma_f32_16x16x32_bf16(a1l[c], brh, acr1[jt], 0, 0, 0);
            aci1[jt] = __builtin_amdgcn_mfma_f32_16x16x32_bf16(a1h[c], bih, aci1[jt], 0, 0, 0);
            aci1[jt] = __builtin_amdgcn_mfma_f32_16x16x32_bf16(a1h[c], bil, aci1[jt], 0, 0, 0);
            aci1[jt] = __builtin_amdgcn_mfma_f32_16x16x32_bf16(a1l[c], bih, aci1[jt], 0, 0, 0);
        }
    }

    // ---- epilogue: C/D layout col=lane&15, row=4*(lane>>4)+reg (HW-verified)
    float iv0[4], iv1[4];
#pragma unroll
    for (int v = 0; v < 4; ++v) {
        iv0[v] = __shfl(inv0, 4 * g + v);
        iv1[v] = __shfl(inv1, 4 * g + v);
    }

    float* op0 = out + (size_t)(row0 + 4 * g) * DIM + r;
    float* op1 = op0 + (size_t)16 * DIM;
#pragma unroll
    for (int v = 0; v < 4; ++v)
#pragma unroll
        for (int jt = 0; jt < 4; ++jt) {
            float yr0 = acr0[jt][v], yi0 = aci0[jt][v];
            float yr1 = acr1[jt][v], yi1 = aci1[jt][v];
            op0[(size_t)v * DIM + jt * 16] = (yr0 * yr0 + yi0 * yi0) * iv0[v];
            op1[(size_t)v * DIM + jt * 16] = (yr1 * yr1 + yi1 * yi1) * iv1[v];
        }
}

extern "C" void kernel_launch(void* const* d_in, const int* in_sizes, int n_in,
                              void* d_out, int out_size, void* d_ws, size_t ws_size,
                              hipStream_t stream) {
    const float* x = (const float*)d_in[0];
    const float* w = (const float*)d_in[1];
    float* out = (float*)d_out;
    unsigned short* Bf = (unsigned short*)d_ws;   // 32 KB fragment image
    int B = in_sizes[0] / DIM;

    hipLaunchKernelGGL(build_M, dim3(DIM), dim3(64), 0, stream, w, Bf);
    hipLaunchKernelGGL(qenc_main, dim3(B / 128), dim3(256), 0, stream, x, Bf, out);
}